// Round 1
// baseline (500.068 us; speedup 1.0000x reference)
//
#include <hip/hip_runtime.h>

#define NPTS 8192
#define DIM  128
#define FMARGIN 1.0f
#define FEPS 1e-16f

// ws layout (floats): [0,8192) S  | [8192,16384) sq | [16384] loss_sum | [16385] count(uint)

__global__ void sq_kernel(const float* __restrict__ feat, float* __restrict__ sq) {
    int lane = threadIdx.x & 63;
    int row  = blockIdx.x * 4 + (threadIdx.x >> 6);
    const float2* p = (const float2*)(feat + (size_t)row * DIM);
    float2 v = p[lane];
    float s = v.x * v.x + v.y * v.y;
#pragma unroll
    for (int off = 32; off > 0; off >>= 1) s += __shfl_down(s, off, 64);
    if (lane == 0) sq[row] = s;
}

// PASS 1: S[i] = sum_j (labels differ) exp(margin - d_ij)
// PASS 2: accumulate hinge^2 over positive pairs + positive-pair count
template <int PASS>
__launch_bounds__(256, 2)
__global__ void pair_kernel(const float* __restrict__ feat,
                            const int* __restrict__ labels,
                            const float* __restrict__ sq,
                            float* __restrict__ S,
                            float* __restrict__ loss_sum,
                            unsigned int* __restrict__ count)
{
    __shared__ float As[32 * 128];   // [kk][i] transposed
    __shared__ float Bs[32 * 128];   // [kk][j] transposed
    __shared__ float redf[4];
    __shared__ unsigned redc[4];

    const int tid = threadIdx.x;
    const int tx = tid & 15, ty = tid >> 4;
    const int ib = blockIdx.y * 128, jb = blockIdx.x * 128;

    float acc[8][8];
#pragma unroll
    for (int a = 0; a < 8; ++a)
#pragma unroll
        for (int b = 0; b < 8; ++b) acc[a][b] = 0.0f;

    for (int k0 = 0; k0 < DIM; k0 += 32) {
        // stage: 128 rows x 32 k-cols each of A and B, transposed to [kk][row]
        {
            const int r = tid >> 1, c2 = tid & 1;
            const float4* ga = (const float4*)(feat + (size_t)(ib + r) * DIM + k0 + c2 * 16);
            const float4* gb = (const float4*)(feat + (size_t)(jb + r) * DIM + k0 + c2 * 16);
#pragma unroll
            for (int q = 0; q < 4; ++q) {
                float4 va = ga[q];
                float4 vb = gb[q];
                const int kk = c2 * 16 + q * 4;
                As[(kk + 0) * 128 + r] = va.x;
                As[(kk + 1) * 128 + r] = va.y;
                As[(kk + 2) * 128 + r] = va.z;
                As[(kk + 3) * 128 + r] = va.w;
                Bs[(kk + 0) * 128 + r] = vb.x;
                Bs[(kk + 1) * 128 + r] = vb.y;
                Bs[(kk + 2) * 128 + r] = vb.z;
                Bs[(kk + 3) * 128 + r] = vb.w;
            }
        }
        __syncthreads();
#pragma unroll 4
        for (int kk = 0; kk < 32; ++kk) {
            float4 a0 = *(const float4*)&As[kk * 128 + ty * 8];
            float4 a1 = *(const float4*)&As[kk * 128 + ty * 8 + 4];
            float4 b0 = *(const float4*)&Bs[kk * 128 + tx * 8];
            float4 b1 = *(const float4*)&Bs[kk * 128 + tx * 8 + 4];
            float a[8] = {a0.x, a0.y, a0.z, a0.w, a1.x, a1.y, a1.z, a1.w};
            float b[8] = {b0.x, b0.y, b0.z, b0.w, b1.x, b1.y, b1.z, b1.w};
#pragma unroll
            for (int ii = 0; ii < 8; ++ii)
#pragma unroll
                for (int jj = 0; jj < 8; ++jj)
                    acc[ii][jj] += a[ii] * b[jj];
        }
        __syncthreads();
    }

    const int i0 = ib + ty * 8;
    const int j0 = jb + tx * 8;

    float sqi[8], sqj[8];
    int li[8], lj[8];
#pragma unroll
    for (int ii = 0; ii < 8; ++ii) { sqi[ii] = sq[i0 + ii]; li[ii] = labels[i0 + ii]; }
#pragma unroll
    for (int jj = 0; jj < 8; ++jj) { sqj[jj] = sq[j0 + jj]; lj[jj] = labels[j0 + jj]; }

    if (PASS == 1) {
#pragma unroll
        for (int ii = 0; ii < 8; ++ii) {
            float s = 0.0f;
#pragma unroll
            for (int jj = 0; jj < 8; ++jj) {
                float d2 = sqi[ii] + sqj[jj] - 2.0f * acc[ii][jj];
                float dist = sqrtf(fmaxf(d2, FEPS));
                if (li[ii] != lj[jj]) s += __expf(FMARGIN - dist);
            }
            // reduce across tx (16 lanes with same ty)
#pragma unroll
            for (int off = 8; off > 0; off >>= 1) s += __shfl_down(s, off, 16);
            if (tx == 0) atomicAdd(&S[i0 + ii], s);
        }
    } else {
        float Si[8], Sj[8];
#pragma unroll
        for (int ii = 0; ii < 8; ++ii) Si[ii] = S[i0 + ii];
#pragma unroll
        for (int jj = 0; jj < 8; ++jj) Sj[jj] = S[j0 + jj];

        float lsum = 0.0f;
        unsigned int c = 0;
#pragma unroll
        for (int ii = 0; ii < 8; ++ii)
#pragma unroll
            for (int jj = 0; jj < 8; ++jj) {
                if (li[ii] == lj[jj]) {
                    float d2 = sqi[ii] + sqj[jj] - 2.0f * acc[ii][jj];
                    float dist = sqrtf(fmaxf(d2, FEPS));
                    float J = __logf(Si[ii] + Sj[jj]) + dist;
                    float h = fmaxf(J, 0.0f);
                    lsum += h * h;
                    c++;
                }
            }
        // wave reduce (64 lanes)
#pragma unroll
        for (int off = 32; off > 0; off >>= 1) {
            lsum += __shfl_down(lsum, off, 64);
            c    += __shfl_down(c, off, 64);
        }
        const int wave = tid >> 6, lane = tid & 63;
        if (lane == 0) { redf[wave] = lsum; redc[wave] = c; }
        __syncthreads();
        if (tid == 0) {
            float tf = redf[0] + redf[1] + redf[2] + redf[3];
            unsigned tc = redc[0] + redc[1] + redc[2] + redc[3];
            atomicAdd(loss_sum, tf);
            atomicAdd(count, tc);
        }
    }
}

__global__ void finalize_kernel(const float* __restrict__ loss_sum,
                                const unsigned int* __restrict__ count,
                                float* __restrict__ out) {
    out[0] = loss_sum[0] / (2.0f * (float)count[0]);
}

extern "C" void kernel_launch(void* const* d_in, const int* in_sizes, int n_in,
                              void* d_out, int out_size, void* d_ws, size_t ws_size,
                              hipStream_t stream) {
    const float* feat  = (const float*)d_in[0];
    const int* labels  = (const int*)d_in[1];

    float* ws          = (float*)d_ws;
    float* S           = ws;
    float* sq          = ws + NPTS;
    float* loss_sum    = ws + 2 * NPTS;
    unsigned int* cnt  = (unsigned int*)(ws + 2 * NPTS + 1);

    hipMemsetAsync(d_ws, 0, (2 * NPTS + 2) * sizeof(float), stream);

    sq_kernel<<<NPTS / 4, 256, 0, stream>>>(feat, sq);

    dim3 grid(NPTS / 128, NPTS / 128);
    pair_kernel<1><<<grid, 256, 0, stream>>>(feat, labels, sq, S, loss_sum, cnt);
    pair_kernel<2><<<grid, 256, 0, stream>>>(feat, labels, sq, S, loss_sum, cnt);

    finalize_kernel<<<1, 1, 0, stream>>>(loss_sum, cnt, (float*)d_out);
}

// Round 2
// 402.098 us; speedup vs baseline: 1.2436x; 1.2436x over previous
//
#include <hip/hip_runtime.h>

#define NPTS 8192
#define DIM  128
#define NCLS 64
#define FEPS 1e-16f

// ws layout (float elements)
#define WS_T     0          // 8192 floats: T_i = sum_{j!=i} exp(1-d_ij)
#define WS_SQ    8192       // 8192 floats: row squared norms
#define WS_P     16384      // 8192 floats: P'_i (same-class part), later S_i
#define WS_CNT   24576      // 64 ints
#define WS_OFFS  24640      // 65 ints (member offsets)
#define WS_POFF  24708      // 65 ints (pair offsets, prefix of cnt^2)
#define WS_CUR   24776      // 64 ints
#define WS_MEM   24840      // 8192 ints (class member lists)
#define WS_LOSS  33032      // 1 float
#define WS_G     33040      // 524288 floats = 2MB bf16 swizzled features (16B aligned)
#define WS_DP    557328     // up to ~2M floats: per-pair distances

typedef float f32x4 __attribute__((ext_vector_type(4)));
typedef short bf16x8 __attribute__((ext_vector_type(8)));

#define GL2LDS16(g, l) \
  __builtin_amdgcn_global_load_lds((__attribute__((address_space(1))) const void*)(g), \
                                   (__attribute__((address_space(3))) void*)(l), 16, 0, 0)

__device__ inline unsigned short f2bf(float x) {
    unsigned u = __float_as_uint(x);
    u += 0x7fffu + ((u >> 16) & 1u);   // RNE
    return (unsigned short)(u >> 16);
}

// dot of two bf16 pairs packed in uints (low u16 = element k, high = k+1)
__device__ inline float bfdot2(unsigned a, unsigned b) {
    float a0 = __uint_as_float(a << 16);
    float a1 = __uint_as_float(a & 0xffff0000u);
    float b0 = __uint_as_float(b << 16);
    float b1 = __uint_as_float(b & 0xffff0000u);
    return fmaf(a0, b0, a1 * b1);
}

// ---- prep: squared norms + bf16 swizzled feature buffer ----
// G layout (bf16/u16 units): tile t=i>>7 (16384 each) | chunk c=k>>3 (1024 each)
//                            | m=i&127 (8 each) | k&7
__global__ void prep_kernel(const float* __restrict__ feat,
                            float* __restrict__ sq,
                            unsigned short* __restrict__ G) {
    int w = threadIdx.x >> 6, lane = threadIdx.x & 63;
    int i = blockIdx.x * 4 + w;
    const float2* row = (const float2*)(feat + (size_t)i * DIM);
    float2 v = row[lane];
    unsigned pack = ((unsigned)f2bf(v.y) << 16) | (unsigned)f2bf(v.x);
    int t = i >> 7, m = i & 127;
    int c = lane >> 2;                      // k = 2*lane, c = k>>3
    int pos = (lane & 3) * 2;               // k&7
    *(unsigned*)(&G[(size_t)t * 16384 + c * 1024 + m * 8 + pos]) = pack;
    float s = v.x * v.x + v.y * v.y;
#pragma unroll
    for (int off = 32; off > 0; off >>= 1) s += __shfl_down(s, off, 64);
    if (lane == 0) sq[i] = s;
}

// ---- class bucketing ----
__global__ void count_kernel(const int* __restrict__ labels, int* __restrict__ cnt) {
    int n = blockIdx.x * 256 + threadIdx.x;
    atomicAdd(&cnt[labels[n]], 1);
}

__global__ void offsets_kernel(const int* __restrict__ cnt,
                               int* __restrict__ offs, int* __restrict__ poff) {
    if (threadIdx.x == 0) {
        int o = 0, p = 0;
        for (int c = 0; c < NCLS; ++c) {
            offs[c] = o; poff[c] = p;
            o += cnt[c]; p += cnt[c] * cnt[c];
        }
        offs[NCLS] = o; poff[NCLS] = p;
    }
}

__global__ void scatter_kernel(const int* __restrict__ labels,
                               const int* __restrict__ offs,
                               int* __restrict__ cur, int* __restrict__ mem) {
    int n = blockIdx.x * 256 + threadIdx.x;
    int c = labels[n];
    int pos = atomicAdd(&cur[c], 1);
    mem[offs[c] + pos] = n;
}

// ---- main N^2 pass: T_i = sum_{j!=i} exp(1 - d_ij), bf16 MFMA ----
__launch_bounds__(256, 2)
__global__ void gemm_T(const uint4* __restrict__ G,
                       const float* __restrict__ sq,
                       float* __restrict__ T) {
    __shared__ uint4 Als[2048];     // 128x128 bf16 A tile, staging order
    __shared__ uint4 Bls[2048];
    __shared__ float sqi[128], sqj[128];

    const int tid = threadIdx.x;
    const int w = tid >> 6, lane = tid & 63;
    const int wr = w >> 1, wc = w & 1;
    const int q = lane >> 4, ml = lane & 15;
    const int ib = blockIdx.y * 128, jb = blockIdx.x * 128;

    const uint4* GA = G + (size_t)(ib >> 7) * 2048;
    const uint4* GB = G + (size_t)(jb >> 7) * 2048;
#pragma unroll
    for (int q2 = 0; q2 < 8; ++q2) {
        int off = w * 512 + q2 * 64;
        GL2LDS16(GA + off + lane, &Als[off]);
        GL2LDS16(GB + off + lane, &Bls[off]);
    }
    if (tid < 128) sqi[tid] = sq[ib + tid];
    else sqj[tid - 128] = sq[jb + tid - 128];
    __syncthreads();

    f32x4 acc[4][4];
#pragma unroll
    for (int a = 0; a < 4; ++a)
#pragma unroll
        for (int b = 0; b < 4; ++b) acc[a][b] = (f32x4){0.f, 0.f, 0.f, 0.f};

    const bf16x8* A8 = (const bf16x8*)Als;
    const bf16x8* B8 = (const bf16x8*)Bls;
#pragma unroll
    for (int s = 0; s < 4; ++s) {
        bf16x8 af[4], bf[4];
        int kbase = (s * 4 + q) * 128;
#pragma unroll
        for (int ii = 0; ii < 4; ++ii) af[ii] = A8[kbase + wr * 64 + ii * 16 + ml];
#pragma unroll
        for (int jj = 0; jj < 4; ++jj) bf[jj] = B8[kbase + wc * 64 + jj * 16 + ml];
#pragma unroll
        for (int ii = 0; ii < 4; ++ii)
#pragma unroll
            for (int jj = 0; jj < 4; ++jj)
                acc[ii][jj] = __builtin_amdgcn_mfma_f32_16x16x32_bf16(af[ii], bf[jj], acc[ii][jj], 0, 0, 0);
    }

    // epilogue: e = exp(1 - d), row sums -> T
#pragma unroll
    for (int ii = 0; ii < 4; ++ii) {
        float rs[4] = {0.f, 0.f, 0.f, 0.f};
        int rl = wr * 64 + ii * 16 + q * 4;      // local row base (rows rl..rl+3)
#pragma unroll
        for (int jj = 0; jj < 4; ++jj) {
            int cl = wc * 64 + jj * 16 + ml;     // local col
            float sj = sqj[cl];
            int j = jb + cl;
#pragma unroll
            for (int r = 0; r < 4; ++r) {
                float d2 = sqi[rl + r] + sj - 2.0f * acc[ii][jj][r];
                float d = sqrtf(fmaxf(d2, FEPS));
                float e = __expf(1.0f - d);
                if (ib + rl + r == j) e = 0.0f;
                rs[r] += e;
            }
        }
#pragma unroll
        for (int m = 1; m < 16; m <<= 1)
#pragma unroll
            for (int r = 0; r < 4; ++r) rs[r] += __shfl_xor(rs[r], m, 64);
        if (ml == 0) {
#pragma unroll
            for (int r = 0; r < 4; ++r) atomicAdd(&T[ib + rl + r], rs[r]);
        }
    }
}

// ---- pair mapping helper ----
__device__ inline void map_pair(int p, const int* poff, const int* cnt,
                                int& c, int& a, int& b) {
    int lo = 0, hi = NCLS - 1;
    while (lo < hi) {
        int mid = (lo + hi + 1) >> 1;
        if (p >= poff[mid]) lo = mid; else hi = mid - 1;
    }
    c = lo;
    unsigned pl = (unsigned)(p - poff[c]);
    unsigned n = (unsigned)cnt[c];
    a = (int)(pl / n);
    b = (int)(pl - (unsigned)a * n);
}

__device__ inline float dot_rows(const uint4* __restrict__ G, int ra, int rb) {
    const uint4* pa = G + ((size_t)(ra >> 7) * 2048 + (ra & 127));
    const uint4* pb = G + ((size_t)(rb >> 7) * 2048 + (rb & 127));
    float s0 = 0.f, s1 = 0.f, s2 = 0.f, s3 = 0.f;
#pragma unroll
    for (int c = 0; c < 16; ++c) {
        uint4 va = pa[(size_t)c * 128];
        uint4 vb = pb[(size_t)c * 128];
        s0 += bfdot2(va.x, vb.x);
        s1 += bfdot2(va.y, vb.y);
        s2 += bfdot2(va.z, vb.z);
        s3 += bfdot2(va.w, vb.w);
    }
    return (s0 + s1) + (s2 + s3);
}

// ---- per-pair pass A: distances + P' accumulation ----
__global__ void pairA_kernel(const uint4* __restrict__ G,
                             const float* __restrict__ sq,
                             const int* __restrict__ cnt, const int* __restrict__ offs,
                             const int* __restrict__ poff, const int* __restrict__ mem,
                             float* __restrict__ P, float* __restrict__ dpair) {
    int total = poff[NCLS];
    int stride = gridDim.x * blockDim.x;
    for (int p = blockIdx.x * blockDim.x + threadIdx.x; p < total; p += stride) {
        int c, a, b;
        map_pair(p, poff, cnt, c, a, b);
        if (a == b) { dpair[p] = 1e-8f; continue; }
        int ia = mem[offs[c] + a], jb_ = mem[offs[c] + b];
        float dot = dot_rows(G, ia, jb_);
        float d2 = sq[ia] + sq[jb_] - 2.0f * dot;
        float d = sqrtf(fmaxf(d2, FEPS));
        dpair[p] = d;
        atomicAdd(&P[ia], __expf(1.0f - d));
    }
}

// ---- S = T - P' (in place into P) ----
__global__ void s_kernel(const float* __restrict__ T, float* __restrict__ P) {
    int i = blockIdx.x * 256 + threadIdx.x;
    P[i] = T[i] - P[i];
}

// ---- per-pair pass B: loss ----
__global__ void pairB_kernel(const float* __restrict__ S,
                             const int* __restrict__ cnt, const int* __restrict__ offs,
                             const int* __restrict__ poff, const int* __restrict__ mem,
                             const float* __restrict__ dpair,
                             float* __restrict__ loss_sum) {
    int total = poff[NCLS];
    int stride = gridDim.x * blockDim.x;
    float lsum = 0.f;
    for (int p = blockIdx.x * blockDim.x + threadIdx.x; p < total; p += stride) {
        int c, a, b;
        map_pair(p, poff, cnt, c, a, b);
        int ia = mem[offs[c] + a], jb_ = mem[offs[c] + b];
        float J = __logf(S[ia] + S[jb_]) + dpair[p];
        float h = fmaxf(J, 0.0f);
        lsum += h * h;
    }
#pragma unroll
    for (int off = 32; off > 0; off >>= 1) lsum += __shfl_down(lsum, off, 64);
    if ((threadIdx.x & 63) == 0) atomicAdd(loss_sum, lsum);
}

__global__ void finalize_kernel(const float* __restrict__ loss_sum,
                                const int* __restrict__ poff,
                                float* __restrict__ out) {
    out[0] = loss_sum[0] / (2.0f * (float)poff[NCLS]);
}

extern "C" void kernel_launch(void* const* d_in, const int* in_sizes, int n_in,
                              void* d_out, int out_size, void* d_ws, size_t ws_size,
                              hipStream_t stream) {
    const float* feat = (const float*)d_in[0];
    const int* labels = (const int*)d_in[1];

    float* ws = (float*)d_ws;
    float* T = ws + WS_T;
    float* sq = ws + WS_SQ;
    float* P = ws + WS_P;
    int* cnt = (int*)(ws + WS_CNT);
    int* offs = (int*)(ws + WS_OFFS);
    int* poff = (int*)(ws + WS_POFF);
    int* cur = (int*)(ws + WS_CUR);
    int* mem = (int*)(ws + WS_MEM);
    float* loss_sum = ws + WS_LOSS;
    unsigned short* G16 = (unsigned short*)(ws + WS_G);
    const uint4* G4 = (const uint4*)(ws + WS_G);
    float* dpair = ws + WS_DP;

    // zero T, P, cnt, cur, loss (sq/offs/mem/poff fully overwritten later)
    hipMemsetAsync(d_ws, 0, (WS_LOSS + 1) * sizeof(float), stream);

    prep_kernel<<<NPTS / 4, 256, 0, stream>>>(feat, sq, G16);
    count_kernel<<<NPTS / 256, 256, 0, stream>>>(labels, cnt);
    offsets_kernel<<<1, 64, 0, stream>>>(cnt, offs, poff);
    scatter_kernel<<<NPTS / 256, 256, 0, stream>>>(labels, offs, cur, mem);

    dim3 grid(NPTS / 128, NPTS / 128);
    gemm_T<<<grid, 256, 0, stream>>>(G4, sq, T);

    pairA_kernel<<<1024, 256, 0, stream>>>(G4, sq, cnt, offs, poff, mem, P, dpair);
    s_kernel<<<NPTS / 256, 256, 0, stream>>>(T, P);
    pairB_kernel<<<1024, 256, 0, stream>>>(P, cnt, offs, poff, mem, dpair, loss_sum);

    finalize_kernel<<<1, 1, 0, stream>>>(loss_sum, poff, (float*)d_out);
}

// Round 3
// 200.593 us; speedup vs baseline: 2.4929x; 2.0045x over previous
//
#include <hip/hip_runtime.h>

#define NPTS 8192
#define DIM  128
#define NCLS 64
#define FEPS 1e-16f

// ws layout (float elements)
#define WS_S     0          // 8192 floats: S_i = sum_{label!=} exp(1-d_ij)
#define WS_SQ    8192       // 8192 floats: row squared norms
#define WS_CNT   16384      // 64 ints
#define WS_OFFS  16448      // 65 ints
#define WS_POFF  16520      // 65 ints (prefix of cnt^2)
#define WS_CUR   16592      // 64 ints
#define WS_MEM   16656      // 8192 ints
#define WS_LOSS  24848      // 1 float
#define WS_G     24852      // 16B aligned (24852*4 = 6213*16): 2MB bf16 swizzled features

typedef float f32x4 __attribute__((ext_vector_type(4)));
typedef short bf16x8 __attribute__((ext_vector_type(8)));

#define GL2LDS16(g, l) \
  __builtin_amdgcn_global_load_lds((__attribute__((address_space(1))) const void*)(g), \
                                   (__attribute__((address_space(3))) void*)(l), 16, 0, 0)

__device__ inline unsigned short f2bf(float x) {
    unsigned u = __float_as_uint(x);
    u += 0x7fffu + ((u >> 16) & 1u);   // RNE
    return (unsigned short)(u >> 16);
}

// ---- prep: squared norms + bf16 swizzled feature buffer ----
// G layout (u16 units): tile t=i>>7 (16384 each) | chunk c=k>>3 (1024 each)
//                       | m=i&127 (8 each) | k&7
__global__ void prep_kernel(const float* __restrict__ feat,
                            float* __restrict__ sq,
                            unsigned short* __restrict__ G) {
    int w = threadIdx.x >> 6, lane = threadIdx.x & 63;
    int i = blockIdx.x * 4 + w;
    const float2* row = (const float2*)(feat + (size_t)i * DIM);
    float2 v = row[lane];
    unsigned pack = ((unsigned)f2bf(v.y) << 16) | (unsigned)f2bf(v.x);
    int t = i >> 7, m = i & 127;
    int c = lane >> 2;
    int pos = (lane & 3) * 2;
    *(unsigned*)(&G[(size_t)t * 16384 + c * 1024 + m * 8 + pos]) = pack;
    float s = v.x * v.x + v.y * v.y;
#pragma unroll
    for (int off = 32; off > 0; off >>= 1) s += __shfl_down(s, off, 64);
    if (lane == 0) sq[i] = s;
}

// ---- class bucketing ----
__global__ void count_kernel(const int* __restrict__ labels, int* __restrict__ cnt) {
    int n = blockIdx.x * 256 + threadIdx.x;
    atomicAdd(&cnt[labels[n]], 1);
}

__global__ void offsets_kernel(const int* __restrict__ cnt,
                               int* __restrict__ offs, int* __restrict__ poff) {
    if (threadIdx.x == 0) {
        int o = 0, p = 0;
        for (int c = 0; c < NCLS; ++c) {
            offs[c] = o; poff[c] = p;
            o += cnt[c]; p += cnt[c] * cnt[c];
        }
        offs[NCLS] = o; poff[NCLS] = p;
    }
}

__global__ void scatter_kernel(const int* __restrict__ labels,
                               const int* __restrict__ offs,
                               int* __restrict__ cur, int* __restrict__ mem) {
    int n = blockIdx.x * 256 + threadIdx.x;
    int c = labels[n];
    int pos = atomicAdd(&cur[c], 1);
    mem[offs[c] + pos] = n;
}

// ---- main N^2 pass (upper-triangular tiles): S_i = sum_{label!=} exp(1-d_ij) ----
__launch_bounds__(256, 2)
__global__ void gemm_S(const uint4* __restrict__ G,
                       const float* __restrict__ sq,
                       const int* __restrict__ labels,
                       float* __restrict__ S) {
    const int bt = blockIdx.y, jt = blockIdx.x;
    if (jt < bt) return;                       // symmetry: upper triangle only

    __shared__ uint4 Als[2048];
    __shared__ uint4 Bls[2048];
    __shared__ float sqi[128], sqj[128];
    __shared__ int lli[128], llj[128];

    const int tid = threadIdx.x;
    const int w = tid >> 6, lane = tid & 63;
    const int wr = w >> 1, wc = w & 1;
    const int q = lane >> 4, ml = lane & 15;
    const int ib = bt * 128, jb = jt * 128;
    const bool diag = (bt == jt);

    const uint4* GA = G + (size_t)bt * 2048;
    const uint4* GB = G + (size_t)jt * 2048;
#pragma unroll
    for (int q2 = 0; q2 < 8; ++q2) {
        int off = w * 512 + q2 * 64;
        GL2LDS16(GA + off + lane, &Als[off]);
        GL2LDS16(GB + off + lane, &Bls[off]);
    }
    if (tid < 128) { sqi[tid] = sq[ib + tid]; lli[tid] = labels[ib + tid]; }
    else { sqj[tid - 128] = sq[jb + tid - 128]; llj[tid - 128] = labels[jb + tid - 128]; }
    __syncthreads();

    f32x4 acc[4][4];
#pragma unroll
    for (int a = 0; a < 4; ++a)
#pragma unroll
        for (int b = 0; b < 4; ++b) acc[a][b] = (f32x4){0.f, 0.f, 0.f, 0.f};

    const bf16x8* A8 = (const bf16x8*)Als;
    const bf16x8* B8 = (const bf16x8*)Bls;
#pragma unroll
    for (int s = 0; s < 4; ++s) {
        bf16x8 af[4], bf[4];
        int kbase = (s * 4 + q) * 128;
#pragma unroll
        for (int ii = 0; ii < 4; ++ii) af[ii] = A8[kbase + wr * 64 + ii * 16 + ml];
#pragma unroll
        for (int jj = 0; jj < 4; ++jj) bf[jj] = B8[kbase + wc * 64 + jj * 16 + ml];
#pragma unroll
        for (int ii = 0; ii < 4; ++ii)
#pragma unroll
            for (int jj = 0; jj < 4; ++jj)
                acc[ii][jj] = __builtin_amdgcn_mfma_f32_16x16x32_bf16(af[ii], bf[jj], acc[ii][jj], 0, 0, 0);
    }

    // epilogue: e = (label differs) ? exp(1-d) : 0 ; row sums always, col sums if off-diag
    float rowsum[4][4];
    float colsum[4] = {0.f, 0.f, 0.f, 0.f};
#pragma unroll
    for (int ii = 0; ii < 4; ++ii)
#pragma unroll
        for (int r = 0; r < 4; ++r) rowsum[ii][r] = 0.f;

    int lcj[4]; float sj[4];
#pragma unroll
    for (int jj = 0; jj < 4; ++jj) {
        int cl = wc * 64 + jj * 16 + ml;
        lcj[jj] = llj[cl]; sj[jj] = sqj[cl];
    }
#pragma unroll
    for (int ii = 0; ii < 4; ++ii) {
        int rl = wr * 64 + ii * 16 + q * 4;
        int lri[4]; float si4[4];
#pragma unroll
        for (int r = 0; r < 4; ++r) { lri[r] = lli[rl + r]; si4[r] = sqi[rl + r]; }
#pragma unroll
        for (int jj = 0; jj < 4; ++jj)
#pragma unroll
            for (int r = 0; r < 4; ++r) {
                float d2 = si4[r] + sj[jj] - 2.0f * acc[ii][jj][r];
                float d = sqrtf(fmaxf(d2, FEPS));
                float e = __expf(1.0f - d);
                float ep = (lri[r] != lcj[jj]) ? e : 0.0f;  // diag auto-excluded (same label)
                rowsum[ii][r] += ep;
                colsum[jj] += ep;
            }
    }
    // row reduce across ml (16 lanes)
#pragma unroll
    for (int ii = 0; ii < 4; ++ii) {
#pragma unroll
        for (int m = 1; m < 16; m <<= 1)
#pragma unroll
            for (int r = 0; r < 4; ++r) rowsum[ii][r] += __shfl_xor(rowsum[ii][r], m, 64);
        if (ml == 0) {
            int rl = wr * 64 + ii * 16 + q * 4;
#pragma unroll
            for (int r = 0; r < 4; ++r) atomicAdd(&S[ib + rl + r], rowsum[ii][r]);
        }
    }
    // col reduce across q (4 subgroups of the wave)
    if (!diag) {
#pragma unroll
        for (int m = 16; m < 64; m <<= 1)
#pragma unroll
            for (int jj = 0; jj < 4; ++jj) colsum[jj] += __shfl_xor(colsum[jj], m, 64);
        if (q == 0) {
#pragma unroll
            for (int jj = 0; jj < 4; ++jj)
                atomicAdd(&S[jb + wc * 64 + jj * 16 + ml], colsum[jj]);
        }
    }
}

// ---- per-class loss: MFMA within-class Gram, J = log(S_i+S_j)+d, hinge^2 ----
__launch_bounds__(256, 2)
__global__ void classloss_kernel(const uint4* __restrict__ G,
                                 const float* __restrict__ sq,
                                 const float* __restrict__ S,
                                 const int* __restrict__ cnt,
                                 const int* __restrict__ offs,
                                 const int* __restrict__ mem,
                                 float* __restrict__ loss_sum) {
    __shared__ uint4 Als[2048];
    __shared__ uint4 Bls[2048];
    __shared__ float sqa[128], Sa[128], sqb[128], Sb[128];
    __shared__ float red[4];

    const int c = blockIdx.x;
    const int n = cnt[c], base = offs[c];
    const int tid = threadIdx.x;
    const int w = tid >> 6, lane = tid & 63;
    const int wr = w >> 1, wc = w & 1;
    const int q = lane >> 4, ml = lane & 15;
    const int nt = (n + 127) >> 7;

    float lsum = 0.f;

    for (int ta = 0; ta < nt; ++ta) {
        // stage A tile (gathered class rows, zero-padded)
        for (int idx = tid; idx < 2048; idx += 256) {
            int ch = idx >> 7, m = idx & 127;
            int a = ta * 128 + m;
            if (a < n) {
                int i = mem[base + a];
                Als[idx] = G[(size_t)(i >> 7) * 2048 + ch * 128 + (i & 127)];
            } else Als[idx] = make_uint4(0, 0, 0, 0);
        }
        if (tid < 128) {
            int a = ta * 128 + tid;
            if (a < n) { int i = mem[base + a]; sqa[tid] = sq[i]; Sa[tid] = S[i]; }
            else { sqa[tid] = 0.f; Sa[tid] = 1.f; }
        }
        for (int tb = 0; tb < nt; ++tb) {
            for (int idx = tid; idx < 2048; idx += 256) {
                int ch = idx >> 7, m = idx & 127;
                int b = tb * 128 + m;
                if (b < n) {
                    int j = mem[base + b];
                    Bls[idx] = G[(size_t)(j >> 7) * 2048 + ch * 128 + (j & 127)];
                } else Bls[idx] = make_uint4(0, 0, 0, 0);
            }
            if (tid < 128) {
                int b = tb * 128 + tid;
                if (b < n) { int j = mem[base + b]; sqb[tid] = sq[j]; Sb[tid] = S[j]; }
                else { sqb[tid] = 0.f; Sb[tid] = 1.f; }
            }
            __syncthreads();

            f32x4 acc[4][4];
#pragma unroll
            for (int a = 0; a < 4; ++a)
#pragma unroll
                for (int b = 0; b < 4; ++b) acc[a][b] = (f32x4){0.f, 0.f, 0.f, 0.f};

            const bf16x8* A8 = (const bf16x8*)Als;
            const bf16x8* B8 = (const bf16x8*)Bls;
#pragma unroll
            for (int s = 0; s < 4; ++s) {
                bf16x8 af[4], bf[4];
                int kbase = (s * 4 + q) * 128;
#pragma unroll
                for (int ii = 0; ii < 4; ++ii) af[ii] = A8[kbase + wr * 64 + ii * 16 + ml];
#pragma unroll
                for (int jj = 0; jj < 4; ++jj) bf[jj] = B8[kbase + wc * 64 + jj * 16 + ml];
#pragma unroll
                for (int ii = 0; ii < 4; ++ii)
#pragma unroll
                    for (int jj = 0; jj < 4; ++jj)
                        acc[ii][jj] = __builtin_amdgcn_mfma_f32_16x16x32_bf16(af[ii], bf[jj], acc[ii][jj], 0, 0, 0);
            }

#pragma unroll
            for (int ii = 0; ii < 4; ++ii) {
                int rl = wr * 64 + ii * 16 + q * 4;
#pragma unroll
                for (int jj = 0; jj < 4; ++jj) {
                    int cl = wc * 64 + jj * 16 + ml;
                    int b = tb * 128 + cl;
#pragma unroll
                    for (int r = 0; r < 4; ++r) {
                        int a = ta * 128 + rl + r;
                        if (a < n && b < n) {
                            float d;
                            if (a == b) d = 1e-8f;   // reference: sqrt(EPS)
                            else {
                                float d2 = sqa[rl + r] + sqb[cl] - 2.0f * acc[ii][jj][r];
                                d = sqrtf(fmaxf(d2, FEPS));
                            }
                            float J = __logf(Sa[rl + r] + Sb[cl]) + d;
                            float h = fmaxf(J, 0.0f);
                            lsum += h * h;
                        }
                    }
                }
            }
            __syncthreads();
        }
    }

    // block reduce
#pragma unroll
    for (int off = 32; off > 0; off >>= 1) lsum += __shfl_down(lsum, off, 64);
    if (lane == 0) red[w] = lsum;
    __syncthreads();
    if (tid == 0) atomicAdd(loss_sum, red[0] + red[1] + red[2] + red[3]);
}

__global__ void finalize_kernel(const float* __restrict__ loss_sum,
                                const int* __restrict__ poff,
                                float* __restrict__ out) {
    out[0] = loss_sum[0] / (2.0f * (float)poff[NCLS]);
}

extern "C" void kernel_launch(void* const* d_in, const int* in_sizes, int n_in,
                              void* d_out, int out_size, void* d_ws, size_t ws_size,
                              hipStream_t stream) {
    const float* feat = (const float*)d_in[0];
    const int* labels = (const int*)d_in[1];

    float* ws = (float*)d_ws;
    float* S = ws + WS_S;
    float* sq = ws + WS_SQ;
    int* cnt = (int*)(ws + WS_CNT);
    int* offs = (int*)(ws + WS_OFFS);
    int* poff = (int*)(ws + WS_POFF);
    int* cur = (int*)(ws + WS_CUR);
    int* mem = (int*)(ws + WS_MEM);
    float* loss_sum = ws + WS_LOSS;
    unsigned short* G16 = (unsigned short*)(ws + WS_G);
    const uint4* G4 = (const uint4*)(ws + WS_G);

    // zero S, cnt, cur, loss (rest fully overwritten)
    hipMemsetAsync(d_ws, 0, (WS_LOSS + 1) * sizeof(float), stream);

    prep_kernel<<<NPTS / 4, 256, 0, stream>>>(feat, sq, G16);
    count_kernel<<<NPTS / 256, 256, 0, stream>>>(labels, cnt);
    offsets_kernel<<<1, 64, 0, stream>>>(cnt, offs, poff);
    scatter_kernel<<<NPTS / 256, 256, 0, stream>>>(labels, offs, cur, mem);

    dim3 grid(NPTS / 128, NPTS / 128);
    gemm_S<<<grid, 256, 0, stream>>>(G4, sq, labels, S);

    classloss_kernel<<<NCLS, 256, 0, stream>>>(G4, sq, S, cnt, offs, mem, loss_sum);

    finalize_kernel<<<1, 1, 0, stream>>>(loss_sum, poff, (float*)d_out);
}